// Round 1
// baseline (362.058 us; speedup 1.0000x reference)
//
#include <hip/hip_runtime.h>
#include <hip/hip_bf16.h>

// MultiRNN: e=E[x]; h_t = tanh(W[z]@e + U[z]@h); logits = h_t@Vw^T + Vb
// N=1024, C=1, H=512, G=16, VOCAB=32000. Outputs: logits f32, h_t f32.

#define N_ROWS  1024
#define H_DIM   512
#define N_GRP   16
#define VOCAB_N 32000

typedef __attribute__((ext_vector_type(4))) float    f32x4;
typedef __attribute__((ext_vector_type(8))) short    short8;
typedef __attribute__((ext_vector_type(8))) __bf16   bf16x8;
typedef __attribute__((ext_vector_type(2))) _Float16 half2;
typedef __attribute__((ext_vector_type(4))) _Float16 half4;
typedef __attribute__((ext_vector_type(8))) _Float16 half8;

__device__ __forceinline__ unsigned short f2bf(float f) {
  unsigned int u = __builtin_bit_cast(unsigned int, f);
  return (unsigned short)((u + 0x7FFFu + ((u >> 16) & 1u)) >> 16);  // RNE
}

__device__ __forceinline__ float fdot2f(half2 a, half2 b, float c) {
#if defined(__has_builtin)
#if __has_builtin(__builtin_amdgcn_fdot2)
  return __builtin_amdgcn_fdot2(a, b, c, false);
#else
  return c + (float)a.x * (float)b.x + (float)a.y * (float)b.y;
#endif
#else
  return c + (float)a.x * (float)b.x + (float)a.y * (float)b.y;
#endif
}

__device__ __forceinline__ f32x4 MFMA16(short8 a, short8 b, f32x4 c) {
  return __builtin_amdgcn_mfma_f32_16x16x32_bf16(
      __builtin_bit_cast(bf16x8, a), __builtin_bit_cast(bf16x8, b), c, 0, 0, 0);
}

// ---------------- kernel 1: counting-sort rows by group ----------------
__global__ void k_sort(const int* __restrict__ z, int* __restrict__ perm,
                       int* __restrict__ offs) {
  __shared__ int cnt[N_GRP], pos[N_GRP];
  const int t = threadIdx.x;  // one thread per row, 1024 threads
  if (t < N_GRP) cnt[t] = 0;
  __syncthreads();
  const int g = z[t];
  atomicAdd(&cnt[g], 1);
  __syncthreads();
  if (t == 0) {
    int acc = 0;
    for (int i = 0; i < N_GRP; ++i) { pos[i] = acc; offs[i] = acc; acc += cnt[i]; }
    offs[N_GRP] = acc;
  }
  __syncthreads();
  const int p = atomicAdd(&pos[g], 1);
  perm[p] = t;
}

// ---------------- kernel 2: We[g][k] = dot(W[g][k][:], E[x][:]) ----------------
__global__ void k_we(const int* __restrict__ x, const float* __restrict__ E,
                     const float* __restrict__ W, float* __restrict__ We) {
  const int gid  = blockIdx.x * blockDim.x + threadIdx.x;
  const int wv   = gid >> 6;          // 0..8191 = g*512 + k
  const int lane = threadIdx.x & 63;
  const f32x4* e4 = (const f32x4*)(E + (size_t)x[0] * H_DIM);
  const f32x4* w4 = (const f32x4*)(W + (size_t)wv * H_DIM);
  f32x4 a0 = w4[lane],      b0 = e4[lane];
  f32x4 a1 = w4[lane + 64], b1 = e4[lane + 64];
  float acc = a0.x * b0.x + a0.y * b0.y + a0.z * b0.z + a0.w * b0.w
            + a1.x * b1.x + a1.y * b1.y + a1.z * b1.z + a1.w * b1.w;
#pragma unroll
  for (int o = 32; o; o >>= 1) acc += __shfl_down(acc, o);
  if (lane == 0) We[wv] = acc;
}

// ---------------- kernel 3: h_t = tanh(We[g] + U[g] @ h[row]), grouped ----------------
// grid = 256: g (16) x ktile (8, 64 k each) x rowhalf (2). f16 LDS + v_dot2.
__global__ __launch_bounds__(256, 1)
void k_ht(const float* __restrict__ h, const float* __restrict__ U,
          const float* __restrict__ We, const int* __restrict__ perm,
          const int* __restrict__ offs, float* __restrict__ ht_out,
          unsigned short* __restrict__ A) {
  __shared__ __align__(16) _Float16 Us[64][520];  // pad 520: conflict-free b128
  __shared__ __align__(16) _Float16 Hs[64][520];
  __shared__ int rowidx[64];

  const int bid = blockIdx.x;
  const int g   = bid & 15;
  const int kt  = (bid >> 4) & 7;
  const int rh  = bid >> 7;
  const int off = offs[g];
  const int cn  = offs[g + 1] - off;
  if (cn <= 0) return;                      // uniform: safe before barriers
  const int hcnt = (cn + 1) >> 1;
  const int r0 = rh * hcnt;
  const int r1 = min(cn, r0 + hcnt);
  if (r0 >= r1) return;

  const int tid = threadIdx.x;
  const int k0  = kt * 64;

  // stage U tile: U[g][k0+k][hh] 64x512 f32 -> f16 (coalesced f32x4)
  {
    const f32x4* src = (const f32x4*)(U + ((size_t)g * H_DIM + k0) * H_DIM);
    for (int idx = tid; idx < 64 * 128; idx += 256) {
      const int k = idx >> 7, h4 = idx & 127;
      f32x4 v = src[(size_t)k * 128 + h4];
      half4 hv;
      hv.x = (_Float16)v.x; hv.y = (_Float16)v.y;
      hv.z = (_Float16)v.z; hv.w = (_Float16)v.w;
      *(half4*)&Us[k][h4 * 4] = hv;
    }
  }

  const int kq = tid & 15;   // thread's k = k0 + kq + 16*a  (a=0..3)
  const int rq = tid >> 4;   // thread's rows i = rq + 16*b   (b=0..3)
  float we[4];
#pragma unroll
  for (int a = 0; a < 4; ++a) we[a] = We[g * H_DIM + k0 + kq + 16 * a];

  for (int p = r0; p < r1; p += 64) {
    __syncthreads();  // prior-pass readers done (also orders Us stage on pass 0)
    if (tid < 64) rowidx[tid] = (p + tid < r1) ? perm[off + p + tid] : -1;
    __syncthreads();
    for (int idx = tid; idx < 64 * 128; idx += 256) {
      const int i = idx >> 7, h4 = idx & 127;
      const int row = rowidx[i];
      if (row >= 0) {
        f32x4 v = *(const f32x4*)(h + (size_t)row * H_DIM + h4 * 4);
        half4 hv;
        hv.x = (_Float16)v.x; hv.y = (_Float16)v.y;
        hv.z = (_Float16)v.z; hv.w = (_Float16)v.w;
        *(half4*)&Hs[i][h4 * 4] = hv;
      }
    }
    __syncthreads();

    int ib[4]; bool vb[4];
#pragma unroll
    for (int b = 0; b < 4; ++b) { ib[b] = rq + 16 * b; vb[b] = (p + rq + 16 * b < r1); }
    float acc[4][4];
#pragma unroll
    for (int a = 0; a < 4; ++a)
#pragma unroll
      for (int b = 0; b < 4; ++b) acc[a][b] = we[a];

    for (int hh = 0; hh < H_DIM; hh += 8) {
      half8 u[4], hv[4];
#pragma unroll
      for (int a = 0; a < 4; ++a) u[a] = *(const half8*)&Us[kq + 16 * a][hh];
#pragma unroll
      for (int b = 0; b < 4; ++b) if (vb[b]) hv[b] = *(const half8*)&Hs[ib[b]][hh];
#pragma unroll
      for (int a = 0; a < 4; ++a)
#pragma unroll
        for (int b = 0; b < 4; ++b) {
          if (vb[b]) {
#pragma unroll
            for (int t = 0; t < 4; ++t) {
              half2 ua; ua.x = u[a][2 * t];  ua.y = u[a][2 * t + 1];
              half2 hb; hb.x = hv[b][2 * t]; hb.y = hv[b][2 * t + 1];
              acc[a][b] = fdot2f(ua, hb, acc[a][b]);
            }
          }
        }
    }

#pragma unroll
    for (int b = 0; b < 4; ++b) {
      if (vb[b]) {
        const int row = rowidx[ib[b]];
#pragma unroll
        for (int a = 0; a < 4; ++a) {
          const int k = k0 + kq + 16 * a;
          const float val = tanhf(acc[a][b]);
          ht_out[(size_t)row * H_DIM + k] = val;       // f32 output
          A[(size_t)row * H_DIM + k]     = f2bf(val);  // bf16 GEMM operand
        }
      }
    }
  }
}

// ---------------- kernel 4: logits = h_t @ Vw^T + Vb (bf16 MFMA) ----------------
// 500 blocks; each owns 64 vocab cols with full K=512 of Vw resident in LDS
// (read once from HBM, fp32->bf16 on the fly). A (h_t bf16, 1MB, L2-resident)
// streams through a double-buffered XOR-swizzled LDS tile (T14 split staging).
__global__ __launch_bounds__(256, 1)
void k_logits(const unsigned short* __restrict__ A, const float* __restrict__ Vw,
              const float* __restrict__ Vb, float* __restrict__ out) {
  __shared__ __align__(16) unsigned short Bs[64 * 512];      // 64KB, swizzled
  __shared__ __align__(16) unsigned short As[2][256 * 64];   // 2x32KB, swizzled

  const int tid  = threadIdx.x;
  const int wid  = tid >> 6;
  const int lane = tid & 63;
  const int lr   = lane & 15;
  const int lk   = lane >> 4;
  const int v0   = blockIdx.x * 64;

  // stage B: Vw[v0..v0+64][0..512] f32 -> bf16, XOR-swizzled rows
  for (int idx = tid; idx < 64 * 64; idx += 256) {
    const int v  = idx >> 6;
    const int k8 = idx & 63;
    const float* s = Vw + (size_t)(v0 + v) * H_DIM + k8 * 8;
    f32x4 x0 = *(const f32x4*)s;
    f32x4 x1 = *(const f32x4*)(s + 4);
    short8 b;
    b[0] = (short)f2bf(x0.x); b[1] = (short)f2bf(x0.y);
    b[2] = (short)f2bf(x0.z); b[3] = (short)f2bf(x0.w);
    b[4] = (short)f2bf(x1.x); b[5] = (short)f2bf(x1.y);
    b[6] = (short)f2bf(x1.z); b[7] = (short)f2bf(x1.w);
    const int byt = v * 1024 + ((k8 * 16) ^ ((v & 7) << 4));
    *(short8*)((char*)Bs + byt) = b;
  }

  float vbr[4];
#pragma unroll
  for (int fn = 0; fn < 4; ++fn) vbr[fn] = Vb[v0 + fn * 16 + lr];

  short8 stg[8];
  // prologue: stage step 0 (mi=0, kb=0)
#pragma unroll
  for (int j = 0; j < 8; ++j) {
    const int c = j * 256 + tid;
    const int r = c >> 3, c16 = c & 7;
    stg[j] = *(const short8*)(A + (size_t)r * H_DIM + c16 * 8);
  }
#pragma unroll
  for (int j = 0; j < 8; ++j) {
    const int c = j * 256 + tid;
    const int r = c >> 3, c16 = c & 7;
    *(short8*)((char*)As[0] + r * 128 + ((c16 * 16) ^ ((r & 7) << 4))) = stg[j];
  }
  __syncthreads();

  f32x4 acc[4][4];
  for (int step = 0; step < 32; ++step) {
    const int mi = step >> 3, kb = step & 7, cur = step & 1;
    if (kb == 0) {
#pragma unroll
      for (int a = 0; a < 4; ++a)
#pragma unroll
        for (int b = 0; b < 4; ++b) acc[a][b] = f32x4{0.f, 0.f, 0.f, 0.f};
    }
    if (step < 31) {  // T14: issue next tile's global loads before compute
      const int ns = step + 1, nmi = ns >> 3, nkb = ns & 7;
#pragma unroll
      for (int j = 0; j < 8; ++j) {
        const int c = j * 256 + tid;
        const int r = c >> 3, c16 = c & 7;
        stg[j] = *(const short8*)(A + (size_t)(nmi * 256 + r) * H_DIM + nkb * 64 + c16 * 8);
      }
    }
    // compute current tile: 2 k-steps x 16 MFMA (4x4 frags per wave)
#pragma unroll
    for (int ks = 0; ks < 2; ++ks) {
      short8 af[4], bfrag[4];
      const int abyt = (ks * 32 + lk * 8) * 2;
      const int kbyt = (kb * 64 + ks * 32 + lk * 8) * 2;
#pragma unroll
      for (int fm = 0; fm < 4; ++fm) {
        const int r = wid * 64 + fm * 16 + lr;
        af[fm] = *(const short8*)((const char*)As[cur] + r * 128 + (abyt ^ ((r & 7) << 4)));
      }
#pragma unroll
      for (int fn = 0; fn < 4; ++fn) {
        const int v = fn * 16 + lr;
        bfrag[fn] = *(const short8*)((const char*)Bs + v * 1024 + (kbyt ^ ((v & 7) << 4)));
      }
#pragma unroll
      for (int fm = 0; fm < 4; ++fm)
#pragma unroll
        for (int fn = 0; fn < 4; ++fn)
          acc[fm][fn] = MFMA16(af[fm], bfrag[fn], acc[fm][fn]);
    }
    if (step < 31) {  // write-late into the other buffer
      const int nb = cur ^ 1;
#pragma unroll
      for (int j = 0; j < 8; ++j) {
        const int c = j * 256 + tid;
        const int r = c >> 3, c16 = c & 7;
        *(short8*)((char*)As[nb] + r * 128 + ((c16 * 16) ^ ((r & 7) << 4))) = stg[j];
      }
    }
    __syncthreads();
    if (kb == 7) {  // epilogue for this m-tile
      const int m0 = mi * 256;
#pragma unroll
      for (int fm = 0; fm < 4; ++fm) {
        const int row = m0 + wid * 64 + fm * 16 + lk * 4;
#pragma unroll
        for (int fn = 0; fn < 4; ++fn) {
          const int col = v0 + fn * 16 + lr;
          float* o = out + (size_t)row * VOCAB_N + col;
#pragma unroll
          for (int r = 0; r < 4; ++r)
            o[(size_t)r * VOCAB_N] = acc[fm][fn][r] + vbr[fn];
        }
      }
    }
  }
}

extern "C" void kernel_launch(void* const* d_in, const int* in_sizes, int n_in,
                              void* d_out, int out_size, void* d_ws, size_t ws_size,
                              hipStream_t stream) {
  const int*   x  = (const int*)d_in[0];
  const int*   z  = (const int*)d_in[1];
  const float* h  = (const float*)d_in[2];
  const float* E  = (const float*)d_in[3];
  const float* W  = (const float*)d_in[4];
  const float* U  = (const float*)d_in[5];
  const float* Vw = (const float*)d_in[6];
  const float* Vb = (const float*)d_in[7];

  float* logits = (float*)d_out;
  float* ht_out = logits + (size_t)N_ROWS * VOCAB_N;

  // workspace layout (~1.09 MB)
  unsigned short* wsA = (unsigned short*)d_ws;                        // 1 MB bf16 h_t
  float* We = (float*)((char*)d_ws + (1 << 20));                      // 32 KB
  int* perm = (int*)((char*)d_ws + (1 << 20) + 32768);                // 4 KB
  int* offs = perm + N_ROWS;                                          // 17 ints

  k_sort<<<1, N_ROWS, 0, stream>>>(z, perm, offs);
  k_we<<<2048, 256, 0, stream>>>(x, E, W, We);
  k_ht<<<256, 256, 0, stream>>>(h, U, We, perm, offs, ht_out, wsA);
  k_logits<<<500, 256, 0, stream>>>(wsA, Vw, Vb, logits);
}

// Round 4
// 315.151 us; speedup vs baseline: 1.1488x; 1.1488x over previous
//
#include <hip/hip_runtime.h>
#include <hip/hip_bf16.h>

// MultiRNN: e=E[x]; h_t = tanh(W[z]@e + U[z]@h); logits = h_t@Vw^T + Vb
// N=1024, C=1, H=512, G=16, VOCAB=32000. Outputs: logits f32, h_t f32.

#define N_ROWS  1024
#define H_DIM   512
#define N_GRP   16
#define VOCAB_N 32000

typedef __attribute__((ext_vector_type(4))) float    f32x4;
typedef __attribute__((ext_vector_type(8))) short    short8;
typedef __attribute__((ext_vector_type(8))) __bf16   bf16x8;

__device__ __forceinline__ unsigned short f2bf(float f) {
  unsigned int u = __builtin_bit_cast(unsigned int, f);
  return (unsigned short)((u + 0x7FFFu + ((u >> 16) & 1u)) >> 16);  // RNE
}

__device__ __forceinline__ short8 cvt8(f32x4 x0, f32x4 x1) {
  short8 b;
  b[0] = (short)f2bf(x0.x); b[1] = (short)f2bf(x0.y);
  b[2] = (short)f2bf(x0.z); b[3] = (short)f2bf(x0.w);
  b[4] = (short)f2bf(x1.x); b[5] = (short)f2bf(x1.y);
  b[6] = (short)f2bf(x1.z); b[7] = (short)f2bf(x1.w);
  return b;
}

__device__ __forceinline__ f32x4 MFMA16(short8 a, short8 b, f32x4 c) {
  return __builtin_amdgcn_mfma_f32_16x16x32_bf16(
      __builtin_bit_cast(bf16x8, a), __builtin_bit_cast(bf16x8, b), c, 0, 0, 0);
}

// ---------------- kernel 1: counting-sort rows by group ----------------
__global__ void k_sort(const int* __restrict__ z, int* __restrict__ perm,
                       int* __restrict__ offs) {
  __shared__ int cnt[N_GRP], pos[N_GRP];
  const int t = threadIdx.x;  // one thread per row, 1024 threads
  if (t < N_GRP) cnt[t] = 0;
  __syncthreads();
  const int g = z[t];
  atomicAdd(&cnt[g], 1);
  __syncthreads();
  if (t == 0) {
    int acc = 0;
    for (int i = 0; i < N_GRP; ++i) { pos[i] = acc; offs[i] = acc; acc += cnt[i]; }
    offs[N_GRP] = acc;
  }
  __syncthreads();
  const int p = atomicAdd(&pos[g], 1);
  perm[p] = t;
}

// ---------------- kernel 2: We[g][k] = dot(W[g][k][:], E[x][:]) ----------------
__global__ void k_we(const int* __restrict__ x, const float* __restrict__ E,
                     const float* __restrict__ W, float* __restrict__ We) {
  const int gid  = blockIdx.x * blockDim.x + threadIdx.x;
  const int wv   = gid >> 6;          // 0..8191 = g*512 + k
  const int lane = threadIdx.x & 63;
  const f32x4* e4 = (const f32x4*)(E + (size_t)x[0] * H_DIM);
  const f32x4* w4 = (const f32x4*)(W + (size_t)wv * H_DIM);
  f32x4 a0 = w4[lane],      b0 = e4[lane];
  f32x4 a1 = w4[lane + 64], b1 = e4[lane + 64];
  float acc = a0.x * b0.x + a0.y * b0.y + a0.z * b0.z + a0.w * b0.w
            + a1.x * b1.x + a1.y * b1.y + a1.z * b1.z + a1.w * b1.w;
#pragma unroll
  for (int o = 32; o; o >>= 1) acc += __shfl_down(acc, o);
  if (lane == 0) We[wv] = acc;
}

// ---------------- kernel 3: h_t = tanh(We[g] + U[g] @ h[row]) as grouped MFMA GEMM ----
// grid = 128: g (16) x nt (8, 64 output-dims each). 256 threads, 4 waves.
// U[g] n-strip staged once in LDS bf16 (swizzled); h fragments read direct from
// global f32 -> bf16; tanh + bias epilogue writes f32 h_t and bf16 A.
__global__ __launch_bounds__(256, 2)
void k_ht(const float* __restrict__ h, const float* __restrict__ U,
          const float* __restrict__ We, const int* __restrict__ perm,
          const int* __restrict__ offs, float* __restrict__ ht_out,
          unsigned short* __restrict__ A) {
  __shared__ __align__(16) unsigned short Us[64 * 512];  // 64KB swizzled
  __shared__ int rowidx[128];

  const int bid = blockIdx.x;
  const int g   = bid & 15;
  const int nt  = bid >> 4;
  const int off = offs[g];
  const int cn  = offs[g + 1] - off;
  if (cn <= 0) return;  // uniform per block, before any barrier

  const int tid  = threadIdx.x;
  const int wid  = tid >> 6;
  const int lane = tid & 63;
  const int lr   = lane & 15;
  const int lk   = lane >> 4;
  const int n0   = nt * 64;

  // stage U[g][n0..n0+64][0..512] f32 -> bf16, XOR-swizzled rows
  const float* ub = U + ((size_t)g * H_DIM + n0) * H_DIM;
  for (int idx = tid; idx < 64 * 64; idx += 256) {
    const int nn = idx >> 6, k8 = idx & 63;
    const float* s = ub + (size_t)nn * H_DIM + k8 * 8;
    f32x4 x0 = *(const f32x4*)s;
    f32x4 x1 = *(const f32x4*)(s + 4);
    *(short8*)((char*)Us + nn * 1024 + ((k8 * 16) ^ ((nn & 7) << 4))) = cvt8(x0, x1);
  }

  float wer[4];
#pragma unroll
  for (int fn = 0; fn < 4; ++fn) wer[fn] = We[g * H_DIM + n0 + fn * 16 + lr];
  const int row0 = perm[off];

  for (int p = 0; p < cn; p += 128) {
    __syncthreads();  // Us ready (1st iter); prior chunk's epilogue done with rowidx
    if (tid < 128) rowidx[tid] = (p + tid < cn) ? perm[off + p + tid] : -1;
    __syncthreads();

    int ra[2];
#pragma unroll
    for (int fm = 0; fm < 2; ++fm) {
      const int rr = rowidx[wid * 32 + fm * 16 + lr];
      ra[fm] = (rr >= 0) ? rr : row0;  // clamp: compute garbage, skip store
    }

    f32x4 acc[2][4];
#pragma unroll
    for (int fm = 0; fm < 2; ++fm)
#pragma unroll
      for (int fn = 0; fn < 4; ++fn) acc[fm][fn] = f32x4{0.f, 0.f, 0.f, 0.f};

#pragma unroll 4
    for (int kf = 0; kf < 16; ++kf) {
      short8 a[2], b[4];
#pragma unroll
      for (int fm = 0; fm < 2; ++fm) {
        const float* s = h + (size_t)ra[fm] * H_DIM + kf * 32 + lk * 8;
        a[fm] = cvt8(*(const f32x4*)s, *(const f32x4*)(s + 4));
      }
#pragma unroll
      for (int fn = 0; fn < 4; ++fn) {
        const int v = fn * 16 + lr;
        b[fn] = *(const short8*)((const char*)Us + v * 1024 +
                                 ((kf * 64 + lk * 16) ^ ((v & 7) << 4)));
      }
#pragma unroll
      for (int fm = 0; fm < 2; ++fm)
#pragma unroll
        for (int fn = 0; fn < 4; ++fn)
          acc[fm][fn] = MFMA16(a[fm], b[fn], acc[fm][fn]);
    }

#pragma unroll
    for (int fm = 0; fm < 2; ++fm)
#pragma unroll
      for (int r = 0; r < 4; ++r) {
        const int row = rowidx[wid * 32 + fm * 16 + lk * 4 + r];
        if (row >= 0) {
#pragma unroll
          for (int fn = 0; fn < 4; ++fn) {
            const int n = n0 + fn * 16 + lr;
            const float val = tanhf(acc[fm][fn][r] + wer[fn]);
            ht_out[(size_t)row * H_DIM + n] = val;
            A[(size_t)row * H_DIM + n]     = f2bf(val);
          }
        }
      }
  }
}

// ---------------- kernel 4: logits = h_t @ Vw^T + Vb (bf16 MFMA) ----------------
// 500 blocks x 256 threads. Only Vw lives in LDS (64KB, staged once, swizzled)
// -> 2 blocks/CU, ZERO barriers in the main loop. A fragments stream direct
// from global (1MB bf16, L2-resident). Per wave: 4 m-tiles of 64 rows x 64 cols;
// per k-step 4 A-loads + 4 ds_read_b128 + 16 MFMA (4x B reuse).
__global__ __launch_bounds__(256, 2)
void k_logits(const unsigned short* __restrict__ A, const float* __restrict__ Vw,
              const float* __restrict__ Vb, float* __restrict__ out) {
  __shared__ __align__(16) unsigned short Bs[64 * 512];  // 64KB swizzled

  const int tid  = threadIdx.x;
  const int wid  = tid >> 6;
  const int lane = tid & 63;
  const int lr   = lane & 15;
  const int lk   = lane >> 4;
  const int v0   = blockIdx.x * 64;

  // stage B: Vw[v0..v0+64][0..512] f32 -> bf16, XOR-swizzled rows
  for (int idx = tid; idx < 64 * 64; idx += 256) {
    const int v  = idx >> 6;
    const int k8 = idx & 63;
    const float* s = Vw + (size_t)(v0 + v) * H_DIM + k8 * 8;
    f32x4 x0 = *(const f32x4*)s;
    f32x4 x1 = *(const f32x4*)(s + 4);
    *(short8*)((char*)Bs + v * 1024 + ((k8 * 16) ^ ((v & 7) << 4))) = cvt8(x0, x1);
  }

  float vbr[4];
#pragma unroll
  for (int fn = 0; fn < 4; ++fn) vbr[fn] = Vb[v0 + fn * 16 + lr];
  __syncthreads();  // the only barrier

  for (int mt = 0; mt < 4; ++mt) {
    const int m0 = wid * 256 + mt * 64;  // wave strip 256 rows, tile 64
    f32x4 acc[4][4];
#pragma unroll
    for (int fm = 0; fm < 4; ++fm)
#pragma unroll
      for (int fn = 0; fn < 4; ++fn) acc[fm][fn] = f32x4{0.f, 0.f, 0.f, 0.f};

#pragma unroll 4
    for (int kf = 0; kf < 16; ++kf) {
      short8 a[4], b[4];
#pragma unroll
      for (int fm = 0; fm < 4; ++fm)
        a[fm] = *(const short8*)(A + (size_t)(m0 + fm * 16 + lr) * H_DIM +
                                 kf * 32 + lk * 8);
#pragma unroll
      for (int fn = 0; fn < 4; ++fn) {
        const int v = fn * 16 + lr;
        b[fn] = *(const short8*)((const char*)Bs + v * 1024 +
                                 ((kf * 64 + lk * 16) ^ ((v & 7) << 4)));
      }
#pragma unroll
      for (int fm = 0; fm < 4; ++fm)
#pragma unroll
        for (int fn = 0; fn < 4; ++fn)
          acc[fm][fn] = MFMA16(a[fm], b[fn], acc[fm][fn]);
    }

#pragma unroll
    for (int fm = 0; fm < 4; ++fm) {
#pragma unroll
      for (int r = 0; r < 4; ++r) {
        const int row = m0 + fm * 16 + lk * 4 + r;
        float* o = out + (size_t)row * VOCAB_N + v0 + lr;
#pragma unroll
        for (int fn = 0; fn < 4; ++fn)
          o[fn * 16] = acc[fm][fn][r] + vbr[fn];
      }
    }
  }
}

extern "C" void kernel_launch(void* const* d_in, const int* in_sizes, int n_in,
                              void* d_out, int out_size, void* d_ws, size_t ws_size,
                              hipStream_t stream) {
  const int*   x  = (const int*)d_in[0];
  const int*   z  = (const int*)d_in[1];
  const float* h  = (const float*)d_in[2];
  const float* E  = (const float*)d_in[3];
  const float* W  = (const float*)d_in[4];
  const float* U  = (const float*)d_in[5];
  const float* Vw = (const float*)d_in[6];
  const float* Vb = (const float*)d_in[7];

  float* logits = (float*)d_out;
  float* ht_out = logits + (size_t)N_ROWS * VOCAB_N;

  // workspace layout (~1.09 MB)
  unsigned short* wsA = (unsigned short*)d_ws;                        // 1 MB bf16 h_t
  float* We = (float*)((char*)d_ws + (1 << 20));                      // 32 KB
  int* perm = (int*)((char*)d_ws + (1 << 20) + 32768);                // 4 KB
  int* offs = perm + N_ROWS;                                          // 17 ints

  k_sort<<<1, N_ROWS, 0, stream>>>(z, perm, offs);
  k_we<<<2048, 256, 0, stream>>>(x, E, W, We);
  k_ht<<<128, 256, 0, stream>>>(h, U, We, perm, offs, ht_out, wsA);
  k_logits<<<500, 256, 0, stream>>>(wsA, Vw, Vb, logits);
}